// Round 3
// baseline (127.805 us; speedup 1.0000x reference)
//
#include <hip/hip_runtime.h>

#define NROWS  256
#define LROW   65536
#define BLOCK  1024
#define VPT    16
#define CHUNK  (BLOCK * VPT)      // 16384
#define NCHUNK (LROW / CHUNK)     // 4

// out = (K0 + prefix(inc) + 2000) / 4000, inc[j] = stress(t[j]) * (t[j+1]-t[j])
// stress(t) = a*exp(-t/(|c|+1e-3)) + b*log1p(t) + d*R*P/T   (t >= 0 here)

__global__ __launch_bounds__(BLOCK)
void stf_scan(const float* __restrict__ x,
              const float* __restrict__ params,
              const float* __restrict__ k0v,
              const float* __restrict__ procc,
              float* __restrict__ out)
{
    const int d    = blockIdx.x;
    const int tid  = threadIdx.x;
    const int lane = tid & 63;
    const int wid  = tid >> 6;          // 0..15

    // per-row constants
    const float pa  = params[d * 4 + 0];
    const float pb  = params[d * 4 + 1];
    const float pcc = params[d * 4 + 2];
    const float pd  = params[d * 4 + 3];
    const float R   = procc[d * 4 + 0];
    const float T   = procc[d * 4 + 1] + 0.1f;
    const float P   = procc[d * 4 + 2];
    const float inv_c = 1.0f / (fabsf(pcc) + 0.001f);
    const float cterm = pd * R * P / T;
    const float k0  = k0v[d];

    __shared__ float ws[2][17];         // double-buffered wave-total scan array

    const float* __restrict__ xrow = x   + (size_t)d * LROW;
    float*       __restrict__ orow = out + (size_t)d * LROW;

    float carry = 0.0f;

    // ---- load chunk 0 ----
    float4 cx0, cx1, cx2, cx3;
    {
        const int s0 = tid * VPT;
        cx0 = *(const float4*)(xrow + s0 + 0);
        cx1 = *(const float4*)(xrow + s0 + 4);
        cx2 = *(const float4*)(xrow + s0 + 8);
        cx3 = *(const float4*)(xrow + s0 + 12);
    }
    float xb = 0.0f;                    // lane-63 boundary value x[s+16]
    if (lane == 63) xb = xrow[tid * VPT + VPT];   // <= 16384, in range

    for (int ch = 0; ch < NCHUNK; ++ch) {
        const int s = ch * CHUNK + tid * VPT;   // row position of first owned elem

        // ---- prefetch next chunk into registers (overlaps with compute) ----
        float4 nx0, nx1, nx2, nx3;
        float nxb = 0.0f;
        const bool havenext = (ch + 1 < NCHUNK);
        if (havenext) {
            const int ns = s + CHUNK;
            nx0 = *(const float4*)(xrow + ns + 0);
            nx1 = *(const float4*)(xrow + ns + 4);
            nx2 = *(const float4*)(xrow + ns + 8);
            nx3 = *(const float4*)(xrow + ns + 12);
            if (lane == 63) {
                const int j16 = ns + VPT;
                if (j16 < LROW) nxb = xrow[j16];
            }
        }

        // boundary element x[s+16]: next thread's first element
        float xn = __shfl_down(cx0.x, 1);
        if (lane == 63) xn = xb;

        float xv[VPT + 1];
        xv[0]  = cx0.x; xv[1]  = cx0.y; xv[2]  = cx0.z; xv[3]  = cx0.w;
        xv[4]  = cx1.x; xv[5]  = cx1.y; xv[6]  = cx1.z; xv[7]  = cx1.w;
        xv[8]  = cx2.x; xv[9]  = cx2.y; xv[10] = cx2.z; xv[11] = cx2.w;
        xv[12] = cx3.x; xv[13] = cx3.y; xv[14] = cx3.z; xv[15] = cx3.w;
        xv[16] = xn;

        // ---- per-thread increments + local inclusive scan ----
        float pref[VPT];
        float run = 0.0f;
        #pragma unroll
        for (int k = 0; k < VPT; ++k) {
            const float t0 = xv[k]     * 500.0f;
            const float t1 = xv[k + 1] * 500.0f;
            const float st = pa * __expf(-t0 * inv_c)
                           + pb * __logf(1.0f + t0)
                           + cterm;
            float inc = st * (t1 - t0);
            if (s + k >= LROW - 1) inc = 0.0f;   // final row position has no increment
            run += inc;
            pref[k] = run;
        }

        // ---- wave inclusive scan of per-thread sums ----
        float v = run;
        #pragma unroll
        for (int off = 1; off < 64; off <<= 1) {
            const float other = __shfl_up(v, off);
            if (lane >= off) v += other;
        }
        const float waveExcl = v - run;

        // ---- block scan of 16 wave totals ----
        const int pbuf = ch & 1;
        if (lane == 63) ws[pbuf][wid] = v;
        __syncthreads();
        if (tid == 0) {
            float acc = 0.0f;
            #pragma unroll
            for (int w = 0; w < 16; ++w) {
                const float t = ws[pbuf][w];
                ws[pbuf][w] = acc;
                acc += t;
            }
            ws[pbuf][16] = acc;
        }
        __syncthreads();

        const float blockExcl = carry + ws[pbuf][wid] + waveExcl;
        const float total     = ws[pbuf][16];

        // ---- outputs: out[s+k] = (k0 + prefix)*(1/4000) + 0.5 ----
        const float basev = k0 + blockExcl;
        float4 o0, o1, o2, o3;
        o0.x = basev;
        o0.y = basev + pref[0];
        o0.z = basev + pref[1];
        o0.w = basev + pref[2];
        o1.x = basev + pref[3];
        o1.y = basev + pref[4];
        o1.z = basev + pref[5];
        o1.w = basev + pref[6];
        o2.x = basev + pref[7];
        o2.y = basev + pref[8];
        o2.z = basev + pref[9];
        o2.w = basev + pref[10];
        o3.x = basev + pref[11];
        o3.y = basev + pref[12];
        o3.z = basev + pref[13];
        o3.w = basev + pref[14];

        const float sc = 2.5e-4f, of = 0.5f;
        o0.x = o0.x * sc + of; o0.y = o0.y * sc + of; o0.z = o0.z * sc + of; o0.w = o0.w * sc + of;
        o1.x = o1.x * sc + of; o1.y = o1.y * sc + of; o1.z = o1.z * sc + of; o1.w = o1.w * sc + of;
        o2.x = o2.x * sc + of; o2.y = o2.y * sc + of; o2.z = o2.z * sc + of; o2.w = o2.w * sc + of;
        o3.x = o3.x * sc + of; o3.y = o3.y * sc + of; o3.z = o3.z * sc + of; o3.w = o3.w * sc + of;

        *(float4*)(orow + s + 0)  = o0;
        *(float4*)(orow + s + 4)  = o1;
        *(float4*)(orow + s + 8)  = o2;
        *(float4*)(orow + s + 12) = o3;

        carry += total;
        if (havenext) { cx0 = nx0; cx1 = nx1; cx2 = nx2; cx3 = nx3; xb = nxb; }
    }
}

extern "C" void kernel_launch(void* const* d_in, const int* in_sizes, int n_in,
                              void* d_out, int out_size, void* d_ws, size_t ws_size,
                              hipStream_t stream) {
    const float* x      = (const float*)d_in[0];   // x_scaled [256*65536]
    const float* params = (const float*)d_in[1];   // [256,4]
    const float* K0     = (const float*)d_in[2];   // [256]
    const float* procc  = (const float*)d_in[3];   // [256,4]
    float* out = (float*)d_out;

    stf_scan<<<NROWS, BLOCK, 0, stream>>>(x, params, K0, procc, out);
}